// Round 1
// 751.190 us; speedup vs baseline: 1.0862x; 1.0862x over previous
//
#include <hip/hip_runtime.h>
#include <cstdint>
#include <cstddef>

// Problem constants (fixed by the reference)
#define N_ROWS  262144
#define FEAT    256
#define NCLUST  512

#define BM      64      // rows per block
#define THREADS 512     // 8 waves; each wave does 64 rows x 64 cols

typedef __attribute__((ext_vector_type(8))) __bf16 bf16x8;
typedef __attribute__((ext_vector_type(4))) float  floatx4;

// fp32 -> bf16 RNE (inputs are finite normals; no NaN handling needed)
__device__ __forceinline__ unsigned short f2bf(float f) {
    union { float f; unsigned u; } v; v.f = f;
    unsigned u = v.u;
    u += 0x7FFFu + ((u >> 16) & 1u);
    return (unsigned short)(u >> 16);
}

// Prep: clusters fp32 [512][256] -> bf16 FRAGMENT-LINEAR cb (ws) + csq[512] (ws)
//
// cb layout (granule = 8 bf16 = 16 B, exactly one lane's MFMA B-fragment):
//   g = (ntile*8 + kk)*64 + lane          with lane = quad*16 + l16
//   cb[g*8 + j] = clusters[ntile*16 + l16][kk*32 + quad*8 + j]
// so a wave's B-load for (ntile, kk) is 64 lanes x 16 B CONTIGUOUS (1 KB),
// instead of 16 scattered 64 B segments at stride 512 B.
__global__ __launch_bounds__(64) void prep_kernel(const float* __restrict__ clusters,
                                                  unsigned short* __restrict__ cb,
                                                  float* __restrict__ csq) {
    const int row = blockIdx.x;
    const int t   = threadIdx.x;              // 0..63, each handles one float4
    const float4* src = (const float4*)(clusters + (size_t)row * FEAT);
    float4 v = src[t];
    float ss = v.x*v.x + v.y*v.y + v.z*v.z + v.w*v.w;
    ushort4 o;
    o.x = f2bf(v.x); o.y = f2bf(v.y); o.z = f2bf(v.z); o.w = f2bf(v.w);

    const int ntile = row >> 4;               // 0..31
    const int l16   = row & 15;
    const int kk    = t >> 3;                 // col/32, 0..7
    const int quad  = (t >> 1) & 3;           // (col/8)&3
    const int half  = t & 1;                  // which float4 of the 8-elem granule
    const size_t g  = (size_t)((ntile * 8 + kk) * 64 + quad * 16 + l16);
    *(ushort4*)(cb + g * 8 + half * 4) = o;

    #pragma unroll
    for (int m = 32; m > 0; m >>= 1) ss += __shfl_xor(ss, m);
    if (t == 0) csq[row] = ss;
}

__global__ __launch_bounds__(THREADS, 4) void cluster_kernel(
    const float* __restrict__ x,
    const unsigned short* __restrict__ cb,   // clusters bf16, fragment-linear
    const float* __restrict__ csq,           // [512]
    float* __restrict__ out)                 // [N][512]
{
    // LDS: A tile (bf16, +8 pad: lane stride 132 dwords -> 2-way bank alias, free)
    __shared__ unsigned short As[BM][FEAT + 8];   // 33792 B
    __shared__ float s_xsq[BM];
    __shared__ float s_rpart[8][BM];
    __shared__ float s_rinv[BM];

    const int tid  = threadIdx.x;
    const int row0 = blockIdx.x * BM;

    // ---- stage x tile -> bf16 LDS, compute per-row ||x||^2 in fp32 ----
    {
        const int r = tid >> 3;   // 0..63 local row
        const int j = tid & 7;    // 8 threads per row
        const float4* xg = (const float4*)(x + (size_t)(row0 + r) * FEAT);
        float ss = 0.f;
        #pragma unroll
        for (int i = 0; i < 8; i++) {
            float4 v = xg[j + 8 * i];
            ss += v.x*v.x + v.y*v.y + v.z*v.z + v.w*v.w;
            ushort4 o;
            o.x = f2bf(v.x); o.y = f2bf(v.y); o.z = f2bf(v.z); o.w = f2bf(v.w);
            *(ushort4*)&As[r][(j + 8 * i) * 4] = o;
        }
        // reduce across the 8 threads sharing a row (contiguous lanes)
        ss += __shfl_xor(ss, 1);
        ss += __shfl_xor(ss, 2);
        ss += __shfl_xor(ss, 4);
        if (j == 0) s_xsq[r] = ss;
    }
    __syncthreads();

    const int wave = tid >> 6;   // 0..7 -> column chunk of 64
    const int lane = tid & 63;
    const int quad = lane >> 4;  // 0..3
    const int l16  = lane & 15;

    floatx4 acc[4][4];
    #pragma unroll
    for (int mt = 0; mt < 4; mt++)
        #pragma unroll
        for (int nt = 0; nt < 4; nt++)
            acc[mt][nt] = (floatx4){0.f, 0.f, 0.f, 0.f};

    // B fragment bases in the fragment-linear layout: per (nt) the granules for
    // kk=0..7 are consecutive 1 KB wave-chunks (stride 512 elems).
    const unsigned short* bq[4];
    #pragma unroll
    for (int nt = 0; nt < 4; nt++)
        bq[nt] = cb + ((size_t)((wave * 4 + nt) * 8) * 64 + lane) * 8;

    // ---- K loop: 8 steps of 32 (unroll 2: enough ILP without blowing the
    //      128-VGPR cap that buys us 2 blocks/CU) ----
    #pragma unroll 2
    for (int s = 0; s < 8; s++) {
        bf16x8 a[4], b[4];
        #pragma unroll
        for (int mt = 0; mt < 4; mt++)
            a[mt] = *(const bf16x8*)&As[mt * 16 + l16][s * 32 + quad * 8];
        #pragma unroll
        for (int nt = 0; nt < 4; nt++)
            b[nt] = *(const bf16x8*)(bq[nt] + (size_t)s * 512);
        #pragma unroll
        for (int mt = 0; mt < 4; mt++)
            #pragma unroll
            for (int nt = 0; nt < 4; nt++)
                acc[mt][nt] = __builtin_amdgcn_mfma_f32_16x16x32_bf16(
                    a[mt], b[nt], acc[mt][nt], 0, 0, 0);
    }

    // ---- epilogue: q = 1/(1+dist2), row-normalize across all 512 cols ----
    float csqv[4];
    #pragma unroll
    for (int nt = 0; nt < 4; nt++)
        csqv[nt] = csq[wave * 64 + nt * 16 + l16];

    #pragma unroll
    for (int mt = 0; mt < 4; mt++) {
        #pragma unroll
        for (int r = 0; r < 4; r++) {
            const int m = mt * 16 + quad * 4 + r;
            float xs = s_xsq[m];
            float rp = 0.f;
            #pragma unroll
            for (int nt = 0; nt < 4; nt++) {
                float d2 = xs + csqv[nt] - 2.0f * acc[mt][nt][r];
                d2 = fmaxf(d2, 0.f);
                float q = __builtin_amdgcn_rcpf(1.0f + d2);
                acc[mt][nt][r] = q;
                rp += q;
            }
            // sum across the 16 column-lanes (butterfly)
            rp += __shfl_xor(rp, 1);
            rp += __shfl_xor(rp, 2);
            rp += __shfl_xor(rp, 4);
            rp += __shfl_xor(rp, 8);
            if (l16 == 0) s_rpart[wave][m] = rp;
        }
    }
    __syncthreads();
    if (tid < BM) {
        float t = 0.f;
        #pragma unroll
        for (int w = 0; w < 8; w++) t += s_rpart[w][tid];
        s_rinv[tid] = __builtin_amdgcn_rcpf(t);
    }
    __syncthreads();

    // ---- store: 16 contiguous lanes per 64B segment ----
    float* op = out + (size_t)row0 * NCLUST + wave * 64 + l16;
    #pragma unroll
    for (int mt = 0; mt < 4; mt++) {
        #pragma unroll
        for (int r = 0; r < 4; r++) {
            const int m = mt * 16 + quad * 4 + r;
            const float inv = s_rinv[m];
            #pragma unroll
            for (int nt = 0; nt < 4; nt++)
                op[(size_t)m * NCLUST + nt * 16] = acc[mt][nt][r] * inv;
        }
    }
}

extern "C" void kernel_launch(void* const* d_in, const int* in_sizes, int n_in,
                              void* d_out, int out_size, void* d_ws, size_t ws_size,
                              hipStream_t stream) {
    const float* x        = (const float*)d_in[0];
    const float* clusters = (const float*)d_in[1];
    unsigned short* cb = (unsigned short*)d_ws;                       // 512*256*2 = 262144 B
    float* csq = (float*)((char*)d_ws + (size_t)NCLUST * FEAT * 2);   // +2048 B
    float* out = (float*)d_out;

    prep_kernel<<<NCLUST, 64, 0, stream>>>(clusters, cb, csq);
    cluster_kernel<<<N_ROWS / BM, THREADS, 0, stream>>>(x, cb, csq, out);
}